// Round 1
// baseline (7384.947 us; speedup 1.0000x reference)
//
#include <hip/hip_runtime.h>
#include <math.h>

// Direct convolution, optionally fused with the following 2x2/2 maxpool
// (torch floor-mode, -inf padding semantics).
// Grid: x = (B*Hout*Wout + 255)/256 threads over batch*spatial,
//       y = Cout/COT  (wave-uniform -> weight/bias loads become s_load).
template<int K, int COT, bool POOL>
__global__ __launch_bounds__(256) void conv_fused(
    const float* __restrict__ in, const float* __restrict__ wgt,
    const float* __restrict__ bias, float* __restrict__ out,
    int B, int Cin, int Hin, int Win,
    int Hc, int Wc, int Hout, int Wout,
    int Cout, int cpad, int ppad)
{
    constexpr int NPY = POOL ? 2 : 1;        // conv positions per dim
    constexpr int PS  = K + NPY - 1;         // input patch size per dim
    const int spatial = Hout * Wout;
    const int idx = blockIdx.x * blockDim.x + threadIdx.x;
    const int total = B * spatial;
    if (idx >= total) return;
    const int b  = idx / spatial;
    const int sp = idx - b * spatial;
    const int oy = sp / Wout;
    const int ox = sp - oy * Wout;
    const int co0 = blockIdx.y * COT;        // wave-uniform

    const int cy0 = POOL ? (2 * oy - ppad) : oy;   // conv-output coords
    const int cx0 = POOL ? (2 * ox - ppad) : ox;
    const int iy0 = cy0 - cpad;                    // input patch origin
    const int ix0 = cx0 - cpad;

    bool my[PS], mx[PS];
#pragma unroll
    for (int i = 0; i < PS; i++) {
        my[i] = (unsigned)(iy0 + i) < (unsigned)Hin;
        mx[i] = (unsigned)(ix0 + i) < (unsigned)Win;
    }

    float acc[COT][NPY * NPY];
#pragma unroll
    for (int c = 0; c < COT; c++)
#pragma unroll
        for (int p = 0; p < NPY * NPY; p++) acc[c][p] = 0.f;

    const long inBase = (long)b * Cin * Hin * Win;
    const long wBase  = (long)co0 * Cin * K * K;

    for (int ci = 0; ci < Cin; ci++) {
        const float* ip = in + inBase + (long)ci * Hin * Win;
        float patch[PS][PS];
#pragma unroll
        for (int py = 0; py < PS; py++) {
#pragma unroll
            for (int px = 0; px < PS; px++) {
                float v = 0.f;
                if (my[py] && mx[px]) v = ip[(iy0 + py) * Win + (ix0 + px)];
                patch[py][px] = v;
            }
        }
        const float* wp = wgt + wBase + (long)ci * K * K;
#pragma unroll
        for (int c = 0; c < COT; c++) {
#pragma unroll
            for (int kh = 0; kh < K; kh++)
#pragma unroll
            for (int kw = 0; kw < K; kw++) {
                const float wv = wp[(long)c * Cin * K * K + kh * K + kw];
#pragma unroll
                for (int dy = 0; dy < NPY; dy++)
#pragma unroll
                for (int dx = 0; dx < NPY; dx++)
                    acc[c][dy * NPY + dx] = fmaf(wv, patch[dy + kh][dx + kw],
                                                 acc[c][dy * NPY + dx]);
            }
        }
    }

#pragma unroll
    for (int c = 0; c < COT; c++) {
        float v;
        if (POOL) {
            v = -INFINITY;
#pragma unroll
            for (int dy = 0; dy < NPY; dy++)
#pragma unroll
            for (int dx = 0; dx < NPY; dx++) {
                const int cy = cy0 + dy, cx = cx0 + dx;
                if ((unsigned)cy < (unsigned)Hc && (unsigned)cx < (unsigned)Wc)
                    v = fmaxf(v, acc[c][dy * NPY + dx]);
            }
        } else {
            v = acc[c][0];
        }
        v += bias[co0 + c];
        out[((long)(b * Cout + co0 + c)) * spatial + sp] = v;
    }
}

// Head: transpose [B,6,13,13] -> [B,13,13,6] into out[0..16223], plus the
// masked-L1 loss scalar into out[16224]. One block, LDS tree reduction.
__global__ __launch_bounds__(1024) void head_kernel(
    const float* __restrict__ x, float* __restrict__ out, int B)
{
    const int W = 13, H = 13;
    const float gx = 0.567f, gy = 0.469f, gw = 0.206f, gh = 0.53f;
    const int tid = threadIdx.x;
    const int total = B * W * H;
    float lsum = 0.f;
    for (int i = tid; i < total; i += blockDim.x) {
        const int b = i / (W * H);
        const int r = i - b * W * H;
        const int j = r / H;        // W index
        const int k = r - j * H;    // H index
        float v[6];
#pragma unroll
        for (int c = 0; c < 6; c++) {
            v[c] = x[((b * 6 + c) * H + k) * W + j];
            out[((b * W + j) * H + k) * 6 + c] = v[c];
        }
        const float px = (j + v[2]) / (float)W;
        const float py = (k + v[3]) / (float)H;
        const float pw = expf(v[4]) / (float)W;
        const float ph = expf(v[5]) / (float)H;
        float iw = fminf(px + pw * 0.5f, gx + gw * 0.5f)
                 - fmaxf(px - pw * 0.5f, gx - gw * 0.5f);
        iw = fmaxf(iw, 0.f);
        float ih = fminf(py + ph * 0.5f, gy + gh * 0.5f)
                 - fmaxf(py - ph * 0.5f, gy - gh * 0.5f);
        ih = fmaxf(ih, 0.f);
        const float inter = iw * ih;
        const float iou = inter / (pw * ph + gw * gh - inter);
        const float tx = gx * W - (float)j;
        const float ty = gy * H - (float)k;
        const float tw = logf(gw * W);
        const float th = logf(gh * H);
        const float l1 = fabsf(tx - v[2]) + fabsf(ty - v[3])
                       + fabsf(tw - v[4]) + fabsf(th - v[5]);
        if (iou > 0.5f) lsum += l1;
    }
    __shared__ float red[1024];
    red[tid] = lsum;
    __syncthreads();
    for (int s = blockDim.x / 2; s > 0; s >>= 1) {
        if (tid < s) red[tid] += red[tid + s];
        __syncthreads();
    }
    if (tid == 0) out[total * 6] = red[0];
}

extern "C" void kernel_launch(void* const* d_in, const int* in_sizes, int n_in,
                              void* d_out, int out_size, void* d_ws, size_t ws_size,
                              hipStream_t stream)
{
    (void)in_sizes; (void)n_in; (void)out_size; (void)ws_size;
    const float* x = (const float*)d_in[0];
    const int B = 16;

    struct L { int cin, cout, k, cpad, pool, ppad; };
    static const L ls[18] = {
        {3,  32, 3, 0, 1, 1}, {32, 64, 3, 0, 1, 1}, {64, 128, 3, 1, 0, 0},
        {128, 64, 1, 0, 0, 0}, {64, 128, 3, 1, 1, 0}, {128, 256, 3, 1, 0, 0},
        {256, 128, 1, 0, 0, 0}, {128, 256, 3, 0, 1, 1}, {256, 512, 3, 1, 0, 0},
        {512, 256, 1, 0, 0, 0}, {256, 512, 3, 1, 0, 0}, {512, 256, 1, 0, 0, 0},
        {256, 512, 3, 0, 1, 1}, {512, 256, 3, 1, 0, 0}, {256, 128, 1, 0, 0, 0},
        {128, 64, 3, 1, 0, 0}, {64, 32, 1, 0, 0, 0}, {32, 6, 3, 1, 0, 0}
    };

    char* ws = (char*)d_ws;
    float* bufA = (float*)ws;                              // needs <= 96 MB
    float* bufB = (float*)(ws + ((size_t)96 << 20));       // needs <= 48 MB

    const float* cur = x;
    int Hin = 416, Win = 416;

    for (int i = 0; i < 18; i++) {
        const L& l = ls[i];
        const int Hc = Hin + 2 * l.cpad - l.k + 1;
        const int Wc = Win + 2 * l.cpad - l.k + 1;
        const int Hout = l.pool ? (Hc + 2 * l.ppad - 2) / 2 + 1 : Hc;
        const int Wout = l.pool ? (Wc + 2 * l.ppad - 2) / 2 + 1 : Wc;
        const int spatial = Hout * Wout;
        float* dst = (i % 2 == 0) ? bufA : bufB;
        const float* w  = (const float*)d_in[2 * i + 1];
        const float* bb = (const float*)d_in[2 * i + 2];

#define LAUNCH(KK, CC, PP)                                                     \
        conv_fused<KK, CC, PP><<<dim3((B * spatial + 255) / 256, l.cout / CC), \
                                 256, 0, stream>>>(                            \
            cur, w, bb, dst, B, l.cin, Hin, Win, Hc, Wc, Hout, Wout,           \
            l.cout, l.cpad, l.ppad)

        if (l.pool)                 LAUNCH(3, 4, true);
        else if (l.k == 3 && l.cout == 6) LAUNCH(3, 6, false);
        else if (l.k == 3)          LAUNCH(3, 8, false);
        else                        LAUNCH(1, 8, false);
#undef LAUNCH

        cur = dst;
        Hin = Hout;
        Win = Wout;
    }

    head_kernel<<<1, 1024, 0, stream>>>(cur, (float*)d_out, B);
}

// Round 2
// 2933.333 us; speedup vs baseline: 2.5176x; 2.5176x over previous
//
#include <hip/hip_runtime.h>
#include <math.h>

typedef short v8s __attribute__((ext_vector_type(8)));
typedef float v4f __attribute__((ext_vector_type(4)));

// ---------------- fp32 direct conv (round-1), kept for layers 1,17,18 + fallback ----
template<int K, int COT, bool POOL>
__global__ __launch_bounds__(256) void conv_fused(
    const float* __restrict__ in, const float* __restrict__ wgt,
    const float* __restrict__ bias, float* __restrict__ out,
    int B, int Cin, int Hin, int Win,
    int Hc, int Wc, int Hout, int Wout,
    int Cout, int cpad, int ppad)
{
    constexpr int NPY = POOL ? 2 : 1;
    constexpr int PS  = K + NPY - 1;
    const int spatial = Hout * Wout;
    const int idx = blockIdx.x * blockDim.x + threadIdx.x;
    const int total = B * spatial;
    if (idx >= total) return;
    const int b  = idx / spatial;
    const int sp = idx - b * spatial;
    const int oy = sp / Wout;
    const int ox = sp - oy * Wout;
    const int co0 = blockIdx.y * COT;

    const int cy0 = POOL ? (2 * oy - ppad) : oy;
    const int cx0 = POOL ? (2 * ox - ppad) : ox;
    const int iy0 = cy0 - cpad;
    const int ix0 = cx0 - cpad;

    bool my[PS], mx[PS];
#pragma unroll
    for (int i = 0; i < PS; i++) {
        my[i] = (unsigned)(iy0 + i) < (unsigned)Hin;
        mx[i] = (unsigned)(ix0 + i) < (unsigned)Win;
    }

    float acc[COT][NPY * NPY];
#pragma unroll
    for (int c = 0; c < COT; c++)
#pragma unroll
        for (int p = 0; p < NPY * NPY; p++) acc[c][p] = 0.f;

    const long inBase = (long)b * Cin * Hin * Win;
    const long wBase  = (long)co0 * Cin * K * K;

    for (int ci = 0; ci < Cin; ci++) {
        const float* ip = in + inBase + (long)ci * Hin * Win;
        float patch[PS][PS];
#pragma unroll
        for (int py = 0; py < PS; py++) {
#pragma unroll
            for (int px = 0; px < PS; px++) {
                float v = 0.f;
                if (my[py] && mx[px]) v = ip[(iy0 + py) * Win + (ix0 + px)];
                patch[py][px] = v;
            }
        }
        const float* wp = wgt + wBase + (long)ci * K * K;
#pragma unroll
        for (int c = 0; c < COT; c++) {
#pragma unroll
            for (int kh = 0; kh < K; kh++)
#pragma unroll
            for (int kw = 0; kw < K; kw++) {
                const float wv = wp[(long)c * Cin * K * K + kh * K + kw];
#pragma unroll
                for (int dy = 0; dy < NPY; dy++)
#pragma unroll
                for (int dx = 0; dx < NPY; dx++)
                    acc[c][dy * NPY + dx] = fmaf(wv, patch[dy + kh][dx + kw],
                                                 acc[c][dy * NPY + dx]);
            }
        }
    }

#pragma unroll
    for (int c = 0; c < COT; c++) {
        float v;
        if (POOL) {
            v = -INFINITY;
#pragma unroll
            for (int dy = 0; dy < NPY; dy++)
#pragma unroll
            for (int dx = 0; dx < NPY; dx++) {
                const int cy = cy0 + dy, cx = cx0 + dx;
                if ((unsigned)cy < (unsigned)Hc && (unsigned)cx < (unsigned)Wc)
                    v = fmaxf(v, acc[c][dy * NPY + dx]);
            }
        } else {
            v = acc[c][0];
        }
        v += bias[co0 + c];
        out[((long)(b * Cout + co0 + c)) * spatial + sp] = v;
    }
}

// ---------------- weight prepack: fp32 OIHW -> MFMA A-frag tiled bf16 hi/lo --------
__device__ __forceinline__ unsigned short f2bf_rne(float x) {
    unsigned u = __float_as_uint(x);
    return (unsigned short)((u + 0x7fffu + ((u >> 16) & 1u)) >> 16);
}
__device__ __forceinline__ float bf2f(unsigned short h) {
    return __uint_as_float(((unsigned)h) << 16);
}

__global__ __launch_bounds__(256) void prepack(
    const float* __restrict__ w, unsigned short* __restrict__ hi,
    unsigned short* __restrict__ lo, int cout, int kdim, int nkb)
{
    int t = blockIdx.x * 256 + threadIdx.x;
    if (t >= cout * kdim) return;
    int co = t / kdim, k = t - co * kdim;
    int cb = co >> 4, m = co & 15, kb = k >> 5, kk = k & 31;
    int lane = ((kk >> 3) << 4) | m, j = kk & 7;
    long dst = ((long)(cb * nkb + kb) << 9) + lane * 8 + j;
    float x = w[t];
    unsigned short h = f2bf_rne(x);
    hi[dst] = h;
    lo[dst] = f2bf_rne(x - bf2f(h));
}

// ---------------- implicit-GEMM conv via MFMA, bf16x2 3-pass split -----------------
// Block: 256 thr (4 waves). C tile = (MT*64 couts) x (64 spatial). K-chunks of 32.
template<int MT, int KS>
__global__ __launch_bounds__(256) void conv_mfma(
    const float* __restrict__ in, const unsigned short* __restrict__ whi,
    const unsigned short* __restrict__ wlo, const float* __restrict__ bias,
    float* __restrict__ out, int Cin, int Hin, int Win, int Hc, int Wc,
    int Cout, int pad, int b0, int nb)
{
    const int HW = Hc * Wc;
    const int M = nb * HW;
    const int tid = threadIdx.x;
    const int lane = tid & 63;
    const int wv = tid >> 6;
    const int spBase = blockIdx.x * 64;
    const int Kdim = Cin * KS * KS;
    const int nkb = Kdim >> 5;
    const int HWin = Hin * Win;

    __shared__ unsigned short Plds[2 * 2560];   // hi @0, lo @2560; row stride 40

    // staging decomposition: this thread touches 4 spatial positions, 2 k-rows/chunk
    const int spoL = (tid & 63) >> 2;
    const int kkl = tid & 3;
    const float* sptr[4];
    int soy[4], sox[4], soff[4];
    bool sval[4];
#pragma unroll
    for (int j = 0; j < 4; ++j) {
        int spo = spoL + 16 * j;
        int sp = spBase + spo;
        sval[j] = sp < M;
        int q = sval[j] ? sp : 0;
        int b = q / HW; int r = q - b * HW;
        soy[j] = r / Wc; sox[j] = r - soy[j] * Wc;
        soff[j] = soy[j] * Win + sox[j];
        sptr[j] = in + (size_t)(b0 + b) * Cin * HWin;
    }

    v4f acc[MT][4];
    {
        v4f z = {0.f, 0.f, 0.f, 0.f};
#pragma unroll
        for (int mt = 0; mt < MT; ++mt)
#pragma unroll
            for (int nt = 0; nt < 4; ++nt) acc[mt][nt] = z;
    }

    for (int kb = 0; kb < nkb; ++kb) {
        int koff[2], dh[2], dw[2];
#pragma unroll
        for (int m = 0; m < 2; ++m) {
            int kk = kkl + 4 * wv + 16 * m;
            int k = kb * 32 + kk;
            int ci;
            if (KS == 3) {
                ci = k / 9; int r9 = k - ci * 9; int d3 = r9 / 3;
                dh[m] = d3 - pad; dw[m] = (r9 - d3 * 3) - pad;
            } else { ci = k; dh[m] = 0; dw[m] = 0; }
            koff[m] = ci * HWin + dh[m] * Win + dw[m];
        }
#pragma unroll
        for (int m = 0; m < 2; ++m)
#pragma unroll
        for (int j = 0; j < 4; ++j) {
            int iy = soy[j] + dh[m], ix = sox[j] + dw[m];
            bool ok = sval[j] && ((unsigned)iy < (unsigned)Hin) &&
                      ((unsigned)ix < (unsigned)Win);
            float v = ok ? sptr[j][koff[m] + soff[j]] : 0.f;
            unsigned vb = __float_as_uint(v);
            float res = v - __uint_as_float(vb & 0xffff0000u);   // truncation split
            int a = (spoL + 16 * j) * 40 + (kkl + 4 * wv + 16 * m);
            Plds[a] = (unsigned short)(vb >> 16);
            Plds[2560 + a] = (unsigned short)(__float_as_uint(res) >> 16);
        }
        __syncthreads();

        v8s wh[MT], wl[MT];
#pragma unroll
        for (int mt = 0; mt < MT; ++mt) {
            size_t wo = ((size_t)((blockIdx.y * (MT * 4) + wv * MT + mt) * nkb + kb) << 9)
                      + lane * 8;
            wh[mt] = *(const v8s*)(whi + wo);
            wl[mt] = *(const v8s*)(wlo + wo);
        }
#pragma unroll
        for (int nt = 0; nt < 4; ++nt) {
            int ro = (nt * 16 + (lane & 15)) * 40 + (lane >> 4) * 8;
            v8s ph = *(const v8s*)(Plds + ro);
            v8s pl = *(const v8s*)(Plds + 2560 + ro);
#pragma unroll
            for (int mt = 0; mt < MT; ++mt) {
                acc[mt][nt] = __builtin_amdgcn_mfma_f32_16x16x32_bf16(wh[mt], ph, acc[mt][nt], 0, 0, 0);
                acc[mt][nt] = __builtin_amdgcn_mfma_f32_16x16x32_bf16(wh[mt], pl, acc[mt][nt], 0, 0, 0);
                acc[mt][nt] = __builtin_amdgcn_mfma_f32_16x16x32_bf16(wl[mt], ph, acc[mt][nt], 0, 0, 0);
            }
        }
        __syncthreads();
    }

    const int qrow = (lane >> 4) * 4;
#pragma unroll
    for (int mt = 0; mt < MT; ++mt) {
        int co = (blockIdx.y * (MT * 4) + wv * MT + mt) * 16 + qrow;
        float bsv[4];
#pragma unroll
        for (int r = 0; r < 4; ++r) bsv[r] = bias[co + r];
#pragma unroll
        for (int nt = 0; nt < 4; ++nt) {
            int sp = spBase + nt * 16 + (lane & 15);
            if (sp < M) {
                int b = sp / HW, rsp = sp - b * HW;
                float* op = out + ((size_t)(b * Cout + co)) * HW + rsp;
#pragma unroll
                for (int r = 0; r < 4; ++r)
                    op[(size_t)r * HW] = acc[mt][nt][r] + bsv[r];
            }
        }
    }
}

// ---------------- standalone 2x2/2 maxpool (torch floor mode, -inf pad) ------------
__global__ __launch_bounds__(256) void maxpool_k(
    const float* __restrict__ in, float* __restrict__ out,
    int C, int Hc, int Wc, int Hp, int Wp, int p, int total)
{
    int t = blockIdx.x * 256 + threadIdx.x;
    if (t >= total) return;
    int wp2 = Hp * Wp;
    int bc = t / wp2; int r = t - bc * wp2;
    int y = r / Wp, xx = r - y * Wp;
    int y0 = 2 * y - p, x0 = 2 * xx - p;
    const float* ip = in + (size_t)bc * Hc * Wc;
    float v = -INFINITY;
#pragma unroll
    for (int dy = 0; dy < 2; ++dy)
#pragma unroll
    for (int dx = 0; dx < 2; ++dx) {
        int yy = y0 + dy, xc = x0 + dx;
        if ((unsigned)yy < (unsigned)Hc && (unsigned)xc < (unsigned)Wc)
            v = fmaxf(v, ip[yy * Wc + xc]);
    }
    out[t] = v;
}

// ---------------- head ------------------------------------------------------------
__global__ __launch_bounds__(1024) void head_kernel(
    const float* __restrict__ x, float* __restrict__ out, int B)
{
    const int W = 13, H = 13;
    const float gx = 0.567f, gy = 0.469f, gw = 0.206f, gh = 0.53f;
    const int tid = threadIdx.x;
    const int total = B * W * H;
    float lsum = 0.f;
    for (int i = tid; i < total; i += blockDim.x) {
        const int b = i / (W * H);
        const int r = i - b * W * H;
        const int j = r / H;
        const int k = r - j * H;
        float v[6];
#pragma unroll
        for (int c = 0; c < 6; c++) {
            v[c] = x[((b * 6 + c) * H + k) * W + j];
            out[((b * W + j) * H + k) * 6 + c] = v[c];
        }
        const float px = (j + v[2]) / (float)W;
        const float py = (k + v[3]) / (float)H;
        const float pw = expf(v[4]) / (float)W;
        const float ph = expf(v[5]) / (float)H;
        float iw = fminf(px + pw * 0.5f, gx + gw * 0.5f)
                 - fmaxf(px - pw * 0.5f, gx - gw * 0.5f);
        iw = fmaxf(iw, 0.f);
        float ih = fminf(py + ph * 0.5f, gy + gh * 0.5f)
                 - fmaxf(py - ph * 0.5f, gy - gh * 0.5f);
        ih = fmaxf(ih, 0.f);
        const float inter = iw * ih;
        const float iou = inter / (pw * ph + gw * gh - inter);
        const float tx = gx * W - (float)j;
        const float ty = gy * H - (float)k;
        const float tw = logf(gw * W);
        const float th = logf(gh * H);
        const float l1 = fabsf(tx - v[2]) + fabsf(ty - v[3])
                       + fabsf(tw - v[4]) + fabsf(th - v[5]);
        if (iou > 0.5f) lsum += l1;
    }
    __shared__ float red[1024];
    red[tid] = lsum;
    __syncthreads();
    for (int s = blockDim.x / 2; s > 0; s >>= 1) {
        if (tid < s) red[tid] += red[tid + s];
        __syncthreads();
    }
    if (tid == 0) out[total * 6] = red[0];
}

// ---------------- host ------------------------------------------------------------
extern "C" void kernel_launch(void* const* d_in, const int* in_sizes, int n_in,
                              void* d_out, int out_size, void* d_ws, size_t ws_size,
                              hipStream_t stream)
{
    (void)in_sizes; (void)n_in; (void)out_size;
    const float* x = (const float*)d_in[0];
    const int B = 16;
    const size_t MB = 1024 * 1024;
    char* ws = (char*)d_ws;
    float* bufA = (float*)ws;                                  // <= 90 MB
    float* bufB = (float*)(ws + 90 * MB);                      // <= 45 MB
    unsigned short* WHI = (unsigned short*)(ws + 135 * MB);    // <= 12 MB
    unsigned short* WLO = (unsigned short*)(ws + 147 * MB);    // <= 12 MB
    char* TEMP = ws + 159 * MB;
    const bool gemmOK = ws_size >= 159 * MB;
    const size_t tempAvail = ws_size > 159 * MB ? ws_size - 159 * MB : 0;

    static const struct { int cin, cout, ks, cpad, pool, ppad; } L[18] = {
        {3,  32, 3, 0, 1, 1}, {32, 64, 3, 0, 1, 1}, {64, 128, 3, 1, 0, 0},
        {128, 64, 1, 0, 0, 0}, {64, 128, 3, 1, 1, 0}, {128, 256, 3, 1, 0, 0},
        {256, 128, 1, 0, 0, 0}, {128, 256, 3, 0, 1, 1}, {256, 512, 3, 1, 0, 0},
        {512, 256, 1, 0, 0, 0}, {256, 512, 3, 1, 0, 0}, {512, 256, 1, 0, 0, 0},
        {256, 512, 3, 0, 1, 1}, {512, 256, 3, 1, 0, 0}, {256, 128, 1, 0, 0, 0},
        {128, 64, 3, 1, 0, 0}, {64, 32, 1, 0, 0, 0}, {32, 6, 3, 1, 0, 0}
    };

    if (gemmOK) {
        size_t off = 0;
        for (int i = 1; i <= 15; ++i) {
            int kdim = L[i].cin * L[i].ks * L[i].ks;
            int n = L[i].cout * kdim;
            prepack<<<(n + 255) / 256, 256, 0, stream>>>(
                (const float*)d_in[2 * i + 1], WHI + off, WLO + off,
                L[i].cout, kdim, kdim / 32);
            off += (size_t)n;
        }
    }

    const float* cur = x;
    int Hin = 416, Win = 416;
    size_t woff = 0;

    for (int i = 0; i < 18; ++i) {
        const auto& l = L[i];
        const int Hc = Hin + 2 * l.cpad - l.ks + 1;
        const int Wc = Win + 2 * l.cpad - l.ks + 1;
        const int Hout = l.pool ? (Hc + 2 * l.ppad - 2) / 2 + 1 : Hc;
        const int Wout = l.pool ? (Wc + 2 * l.ppad - 2) / 2 + 1 : Wc;
        float* dst = (i % 2 == 0) ? bufA : bufB;
        const float* w  = (const float*)d_in[2 * i + 1];
        const float* bb = (const float*)d_in[2 * i + 2];
        const int kdim = l.cin * l.ks * l.ks;

        int nb = 16;
        if (l.pool) {
            size_t perImg = (size_t)l.cout * Hc * Wc * 4;
            while (nb && perImg * (size_t)nb > tempAvail) nb >>= 1;
        }
        const bool useG = gemmOK && i >= 1 && i <= 15 && (!l.pool || nb >= 1);

        if (useG) {
            const int MTv = l.cout >= 256 ? 4 : (l.cout == 128 ? 2 : 1);
            for (int b0 = 0; b0 < B; b0 += nb) {
                const int M = nb * Hc * Wc;
                float* gout = l.pool ? (float*)TEMP : dst;
                dim3 gr((M + 63) / 64, l.cout / (MTv * 64));
#define GLAUNCH(MTC, KSC)                                                     \
                conv_mfma<MTC, KSC><<<gr, 256, 0, stream>>>(                   \
                    cur, WHI + woff, WLO + woff, bb, gout, l.cin, Hin, Win,    \
                    Hc, Wc, l.cout, l.cpad, b0, nb)
                if (MTv == 4 && l.ks == 3)      GLAUNCH(4, 3);
                else if (MTv == 4)              GLAUNCH(4, 1);
                else if (MTv == 2 && l.ks == 3) GLAUNCH(2, 3);
                else if (MTv == 2)              GLAUNCH(2, 1);
                else if (l.ks == 3)             GLAUNCH(1, 3);
                else                            GLAUNCH(1, 1);
#undef GLAUNCH
                if (l.pool) {
                    int total = nb * l.cout * Hout * Wout;
                    maxpool_k<<<(total + 255) / 256, 256, 0, stream>>>(
                        (const float*)TEMP,
                        dst + (size_t)b0 * l.cout * Hout * Wout,
                        l.cout, Hc, Wc, Hout, Wout, l.ppad, total);
                }
            }
        } else {
            const int spatial = Hout * Wout;
#define FLAUNCH(KK, CC, PP)                                                    \
            conv_fused<KK, CC, PP><<<dim3((B * spatial + 255) / 256,           \
                                          l.cout / CC), 256, 0, stream>>>(     \
                cur, w, bb, dst, B, l.cin, Hin, Win, Hc, Wc, Hout, Wout,       \
                l.cout, l.cpad, l.ppad)
            if (l.pool)                           FLAUNCH(3, 4, true);
            else if (l.ks == 3 && l.cout == 6)    FLAUNCH(3, 6, false);
            else if (l.ks == 3)                   FLAUNCH(3, 8, false);
            else                                  FLAUNCH(1, 8, false);
#undef FLAUNCH
        }

        if (i >= 1 && i <= 15) woff += (size_t)l.cout * kdim;
        cur = dst;
        Hin = Hout;
        Win = Wout;
    }

    head_kernel<<<1, 1024, 0, stream>>>(cur, (float*)d_out, B);
}

// Round 3
// 1544.007 us; speedup vs baseline: 4.7830x; 1.8998x over previous
//
#include <hip/hip_runtime.h>
#include <math.h>

typedef short v8s __attribute__((ext_vector_type(8)));
typedef float v4f __attribute__((ext_vector_type(4)));

// ---------------- fp32 direct conv (layers 1,17,18 + fallback) --------------------
template<int K, int COT, bool POOL>
__global__ __launch_bounds__(256) void conv_fused(
    const float* __restrict__ in, const float* __restrict__ wgt,
    const float* __restrict__ bias, float* __restrict__ out,
    int B, int Cin, int Hin, int Win,
    int Hc, int Wc, int Hout, int Wout,
    int Cout, int cpad, int ppad)
{
    constexpr int NPY = POOL ? 2 : 1;
    constexpr int PS  = K + NPY - 1;
    const int spatial = Hout * Wout;
    const int idx = blockIdx.x * blockDim.x + threadIdx.x;
    const int total = B * spatial;
    if (idx >= total) return;
    const int b  = idx / spatial;
    const int sp = idx - b * spatial;
    const int oy = sp / Wout;
    const int ox = sp - oy * Wout;
    const int co0 = blockIdx.y * COT;

    const int cy0 = POOL ? (2 * oy - ppad) : oy;
    const int cx0 = POOL ? (2 * ox - ppad) : ox;
    const int iy0 = cy0 - cpad;
    const int ix0 = cx0 - cpad;

    bool my[PS], mx[PS];
#pragma unroll
    for (int i = 0; i < PS; i++) {
        my[i] = (unsigned)(iy0 + i) < (unsigned)Hin;
        mx[i] = (unsigned)(ix0 + i) < (unsigned)Win;
    }

    float acc[COT][NPY * NPY];
#pragma unroll
    for (int c = 0; c < COT; c++)
#pragma unroll
        for (int p = 0; p < NPY * NPY; p++) acc[c][p] = 0.f;

    const long inBase = (long)b * Cin * Hin * Win;
    const long wBase  = (long)co0 * Cin * K * K;

    for (int ci = 0; ci < Cin; ci++) {
        const float* ip = in + inBase + (long)ci * Hin * Win;
        float patch[PS][PS];
#pragma unroll
        for (int py = 0; py < PS; py++) {
#pragma unroll
            for (int px = 0; px < PS; px++) {
                float v = 0.f;
                if (my[py] && mx[px]) v = ip[(iy0 + py) * Win + (ix0 + px)];
                patch[py][px] = v;
            }
        }
        const float* wp = wgt + wBase + (long)ci * K * K;
#pragma unroll
        for (int c = 0; c < COT; c++) {
#pragma unroll
            for (int kh = 0; kh < K; kh++)
#pragma unroll
            for (int kw = 0; kw < K; kw++) {
                const float wv = wp[(long)c * Cin * K * K + kh * K + kw];
#pragma unroll
                for (int dy = 0; dy < NPY; dy++)
#pragma unroll
                for (int dx = 0; dx < NPY; dx++)
                    acc[c][dy * NPY + dx] = fmaf(wv, patch[dy + kh][dx + kw],
                                                 acc[c][dy * NPY + dx]);
            }
        }
    }

#pragma unroll
    for (int c = 0; c < COT; c++) {
        float v;
        if (POOL) {
            v = -INFINITY;
#pragma unroll
            for (int dy = 0; dy < NPY; dy++)
#pragma unroll
            for (int dx = 0; dx < NPY; dx++) {
                const int cy = cy0 + dy, cx = cx0 + dx;
                if ((unsigned)cy < (unsigned)Hc && (unsigned)cx < (unsigned)Wc)
                    v = fmaxf(v, acc[c][dy * NPY + dx]);
            }
        } else {
            v = acc[c][0];
        }
        v += bias[co0 + c];
        out[((long)(b * Cout + co0 + c)) * spatial + sp] = v;
    }
}

// ---------------- weight prepack: fp32 OIHW -> MFMA A-frag tiled bf16 hi/lo --------
__device__ __forceinline__ unsigned short f2bf_rne(float x) {
    unsigned u = __float_as_uint(x);
    return (unsigned short)((u + 0x7fffu + ((u >> 16) & 1u)) >> 16);
}
__device__ __forceinline__ float bf2f(unsigned short h) {
    return __uint_as_float(((unsigned)h) << 16);
}

__global__ __launch_bounds__(256) void prepack(
    const float* __restrict__ w, unsigned short* __restrict__ hi,
    unsigned short* __restrict__ lo, int cout, int kdim, int nkb)
{
    int t = blockIdx.x * 256 + threadIdx.x;
    if (t >= cout * kdim) return;
    int co = t / kdim, k = t - co * kdim;
    int cb = co >> 4, m = co & 15, kb = k >> 5, kk = k & 31;
    int lane = ((kk >> 3) << 4) | m, j = kk & 7;
    long dst = ((long)(cb * nkb + kb) << 9) + lane * 8 + j;
    float x = w[t];
    unsigned short h = f2bf_rne(x);
    hi[dst] = h;
    lo[dst] = f2bf_rne(x - bf2f(h));
}

// ---------------- implicit-GEMM conv via MFMA, pipelined, bf16x2 3-pass ------------
// Block: 256 thr (4 waves). C tile = (MT*64 couts) x (64 spatial). K-chunks of 32.
// Double-buffered LDS, one barrier per chunk; staging gathers for chunk k+1
// overlap MFMA of chunk k. SPLIT: blockIdx.z = K-slice, partials to 'out'.
template<int MT, int KS, bool SPLIT>
__global__ __launch_bounds__(256) void conv_mfma(
    const float* __restrict__ in, const unsigned short* __restrict__ whi,
    const unsigned short* __restrict__ wlo, const float* __restrict__ bias,
    float* __restrict__ out, int Cin, int Hin, int Win, int Hc, int Wc,
    int Cout, int pad, int b0, int nb, int nkbTot, int nkbPer, int Mpad)
{
    const int HW = Hc * Wc;
    const int M = nb * HW;
    const int tid = threadIdx.x;
    const int lane = tid & 63;
    const int wv = tid >> 6;
    const int spBase = blockIdx.x * 64;
    const int HWin = Hin * Win;
    const int kb0 = SPLIT ? blockIdx.z * nkbPer : 0;
    const int kb1 = SPLIT ? kb0 + nkbPer : nkbTot;

    __shared__ unsigned short P[2][5120];   // per buf: hi rows @0, lo @2560; stride 40

    const int spoL = lane >> 2;
    int kkc[2];
    kkc[0] = (tid & 3) + 4 * wv;
    kkc[1] = kkc[0] + 16;

    const float* sptr[4];
    int soy[4], sox[4], soff[4];
    bool sval[4];
#pragma unroll
    for (int j = 0; j < 4; ++j) {
        int spo = spoL + 16 * j;
        int sp = spBase + spo;
        sval[j] = sp < M;
        int q = sval[j] ? sp : 0;
        int b = q / HW; int r = q - b * HW;
        soy[j] = r / Wc; sox[j] = r - soy[j] * Wc;
        soff[j] = soy[j] * Win + sox[j];
        sptr[j] = in + (size_t)(b0 + b) * Cin * HWin;
    }

    // incremental k-index state (avoids per-chunk divides)
    int ci[2], r9[2], dh[2], dw[2], koff[2];
#pragma unroll
    for (int m = 0; m < 2; ++m) {
        int k = kb0 * 32 + kkc[m];
        if (KS == 3) {
            ci[m] = k / 9; r9[m] = k - 9 * ci[m];
            int d3 = (r9[m] >= 3) + (r9[m] >= 6);
            dh[m] = d3 - pad; dw[m] = r9[m] - 3 * d3 - pad;
        } else { ci[m] = k; dh[m] = 0; dw[m] = 0; }
        koff[m] = ci[m] * HWin + dh[m] * Win + dw[m];
    }

    float rv[8];
#define STAGE()                                                                \
    {                                                                          \
        _Pragma("unroll")                                                      \
        for (int m = 0; m < 2; ++m)                                            \
        _Pragma("unroll")                                                      \
        for (int j = 0; j < 4; ++j) {                                          \
            int iy = soy[j] + dh[m], ix = sox[j] + dw[m];                      \
            bool ok = sval[j] && ((unsigned)iy < (unsigned)Hin) &&             \
                      ((unsigned)ix < (unsigned)Win);                          \
            rv[m * 4 + j] = ok ? sptr[j][koff[m] + soff[j]] : 0.f;             \
        }                                                                      \
    }
#define ADVANCE()                                                              \
    {                                                                          \
        _Pragma("unroll")                                                      \
        for (int m = 0; m < 2; ++m) {                                          \
            if (KS == 3) {                                                     \
                r9[m] += 5; int c = r9[m] >= 9; r9[m] -= c ? 9 : 0;            \
                ci[m] += 3 + c;                                                \
                int d3 = (r9[m] >= 3) + (r9[m] >= 6);                          \
                dh[m] = d3 - pad; dw[m] = r9[m] - 3 * d3 - pad;                \
                koff[m] = ci[m] * HWin + dh[m] * Win + dw[m];                  \
            } else { koff[m] += 32 * HWin; }                                   \
        }                                                                      \
    }

    STAGE();   // chunk kb0

    const int g0 = blockIdx.y * (MT * 4) + wv * MT;
    const unsigned short* whp[MT];
    const unsigned short* wlp[MT];
#pragma unroll
    for (int mt = 0; mt < MT; ++mt) {
        size_t base = (((size_t)(g0 + mt) * nkbTot + kb0) << 9) + lane * 8;
        whp[mt] = whi + base; wlp[mt] = wlo + base;
    }

    v4f acc[MT][4];
    {
        v4f z = {0.f, 0.f, 0.f, 0.f};
#pragma unroll
        for (int mt = 0; mt < MT; ++mt)
#pragma unroll
            for (int nt = 0; nt < 4; ++nt) acc[mt][nt] = z;
    }

    for (int kb = kb0; kb < kb1; ++kb) {
        unsigned short* Ph = P[kb & 1];
#pragma unroll
        for (int m = 0; m < 2; ++m)
#pragma unroll
        for (int j = 0; j < 4; ++j) {
            float v = rv[m * 4 + j];
            unsigned vb = __float_as_uint(v);
            float res = v - __uint_as_float(vb & 0xffff0000u);
            int a = (spoL + 16 * j) * 40 + kkc[m];
            Ph[a] = (unsigned short)(vb >> 16);
            Ph[2560 + a] = (unsigned short)(__float_as_uint(res) >> 16);
        }
        __syncthreads();

        v8s wh[MT], wl[MT];
#pragma unroll
        for (int mt = 0; mt < MT; ++mt) {
            wh[mt] = *(const v8s*)whp[mt];
            wl[mt] = *(const v8s*)wlp[mt];
            whp[mt] += 512; wlp[mt] += 512;
        }

        if (kb + 1 < kb1) { ADVANCE(); STAGE(); }   // overlaps MFMA below

#pragma unroll
        for (int nt = 0; nt < 4; ++nt) {
            int ro = (nt * 16 + (lane & 15)) * 40 + (lane >> 4) * 8;
            v8s ph = *(const v8s*)(Ph + ro);
            v8s pl = *(const v8s*)(Ph + 2560 + ro);
#pragma unroll
            for (int mt = 0; mt < MT; ++mt) {
                acc[mt][nt] = __builtin_amdgcn_mfma_f32_16x16x32_bf16(wh[mt], ph, acc[mt][nt], 0, 0, 0);
                acc[mt][nt] = __builtin_amdgcn_mfma_f32_16x16x32_bf16(wh[mt], pl, acc[mt][nt], 0, 0, 0);
                acc[mt][nt] = __builtin_amdgcn_mfma_f32_16x16x32_bf16(wl[mt], ph, acc[mt][nt], 0, 0, 0);
            }
        }
    }
#undef STAGE
#undef ADVANCE

    const int qrow = (lane >> 4) * 4;
    if (SPLIT) {
        float* pz = out + (size_t)blockIdx.z * Cout * Mpad;
#pragma unroll
        for (int mt = 0; mt < MT; ++mt) {
            int co = (g0 + mt) * 16 + qrow;
#pragma unroll
            for (int nt = 0; nt < 4; ++nt) {
                int sp = spBase + nt * 16 + (lane & 15);
                if (sp < M) {
#pragma unroll
                    for (int r = 0; r < 4; ++r)
                        pz[(size_t)(co + r) * Mpad + sp] = acc[mt][nt][r];
                }
            }
        }
    } else {
#pragma unroll
        for (int mt = 0; mt < MT; ++mt) {
            int co = (g0 + mt) * 16 + qrow;
            float bsv[4];
#pragma unroll
            for (int r = 0; r < 4; ++r) bsv[r] = bias[co + r];
#pragma unroll
            for (int nt = 0; nt < 4; ++nt) {
                int sp = spBase + nt * 16 + (lane & 15);
                if (sp < M) {
                    int b = sp / HW, rsp = sp - b * HW;
                    float* op = out + ((size_t)(b * Cout + co)) * HW + rsp;
#pragma unroll
                    for (int r = 0; r < 4; ++r)
                        op[(size_t)r * HW] = acc[mt][nt][r] + bsv[r];
                }
            }
        }
    }
}

// ---------------- split-K reduce (adds bias) ---------------------------------------
__global__ __launch_bounds__(256) void sk_reduce(
    const float* __restrict__ part, const float* __restrict__ bias,
    float* __restrict__ out, int Cout, int HW, int M, int Mpad, int SK)
{
    int t = blockIdx.x * 256 + threadIdx.x;
    if (t >= Cout * M) return;
    int co = t / M, m = t - co * M;
    float s = bias[co];
    for (int k = 0; k < SK; ++k)
        s += part[((size_t)k * Cout + co) * Mpad + m];
    int b = m / HW, rsp = m - b * HW;
    out[((size_t)(b * Cout + co)) * HW + rsp] = s;
}

// ---------------- standalone 2x2/2 maxpool (torch floor mode, -inf pad) ------------
__global__ __launch_bounds__(256) void maxpool_k(
    const float* __restrict__ in, float* __restrict__ out,
    int C, int Hc, int Wc, int Hp, int Wp, int p, int total)
{
    int t = blockIdx.x * 256 + threadIdx.x;
    if (t >= total) return;
    int wp2 = Hp * Wp;
    int bc = t / wp2; int r = t - bc * wp2;
    int y = r / Wp, xx = r - y * Wp;
    int y0 = 2 * y - p, x0 = 2 * xx - p;
    const float* ip = in + (size_t)bc * Hc * Wc;
    float v = -INFINITY;
#pragma unroll
    for (int dy = 0; dy < 2; ++dy)
#pragma unroll
    for (int dx = 0; dx < 2; ++dx) {
        int yy = y0 + dy, xc = x0 + dx;
        if ((unsigned)yy < (unsigned)Hc && (unsigned)xc < (unsigned)Wc)
            v = fmaxf(v, ip[yy * Wc + xc]);
    }
    out[t] = v;
}

// ---------------- head ------------------------------------------------------------
__global__ __launch_bounds__(1024) void head_kernel(
    const float* __restrict__ x, float* __restrict__ out, int B)
{
    const int W = 13, H = 13;
    const float gx = 0.567f, gy = 0.469f, gw = 0.206f, gh = 0.53f;
    const int tid = threadIdx.x;
    const int total = B * W * H;
    float lsum = 0.f;
    for (int i = tid; i < total; i += blockDim.x) {
        const int b = i / (W * H);
        const int r = i - b * W * H;
        const int j = r / H;
        const int k = r - j * H;
        float v[6];
#pragma unroll
        for (int c = 0; c < 6; c++) {
            v[c] = x[((b * 6 + c) * H + k) * W + j];
            out[((b * W + j) * H + k) * 6 + c] = v[c];
        }
        const float px = (j + v[2]) / (float)W;
        const float py = (k + v[3]) / (float)H;
        const float pw = expf(v[4]) / (float)W;
        const float ph = expf(v[5]) / (float)H;
        float iw = fminf(px + pw * 0.5f, gx + gw * 0.5f)
                 - fmaxf(px - pw * 0.5f, gx - gw * 0.5f);
        iw = fmaxf(iw, 0.f);
        float ih = fminf(py + ph * 0.5f, gy + gh * 0.5f)
                 - fmaxf(py - ph * 0.5f, gy - gh * 0.5f);
        ih = fmaxf(ih, 0.f);
        const float inter = iw * ih;
        const float iou = inter / (pw * ph + gw * gh - inter);
        const float tx = gx * W - (float)j;
        const float ty = gy * H - (float)k;
        const float tw = logf(gw * W);
        const float th = logf(gh * H);
        const float l1 = fabsf(tx - v[2]) + fabsf(ty - v[3])
                       + fabsf(tw - v[4]) + fabsf(th - v[5]);
        if (iou > 0.5f) lsum += l1;
    }
    __shared__ float red[1024];
    red[tid] = lsum;
    __syncthreads();
    for (int s = blockDim.x / 2; s > 0; s >>= 1) {
        if (tid < s) red[tid] += red[tid + s];
        __syncthreads();
    }
    if (tid == 0) out[total * 6] = red[0];
}

// ---------------- host ------------------------------------------------------------
extern "C" void kernel_launch(void* const* d_in, const int* in_sizes, int n_in,
                              void* d_out, int out_size, void* d_ws, size_t ws_size,
                              hipStream_t stream)
{
    (void)in_sizes; (void)n_in; (void)out_size;
    const float* x = (const float*)d_in[0];
    const int B = 16;
    const size_t MB = 1024 * 1024;
    char* ws = (char*)d_ws;
    float* bufA = (float*)ws;                                  // <= 90 MB
    float* bufB = (float*)(ws + 90 * MB);                      // <= 45 MB
    unsigned short* WHI = (unsigned short*)(ws + 135 * MB);    // <= 12 MB
    unsigned short* WLO = (unsigned short*)(ws + 147 * MB);    // <= 12 MB
    char* TEMP = ws + 159 * MB;
    const bool gemmOK = ws_size >= 159 * MB;
    const size_t tempAvail = ws_size > 159 * MB ? ws_size - 159 * MB : 0;

    static const struct { int cin, cout, ks, cpad, pool, ppad; } L[18] = {
        {3,  32, 3, 0, 1, 1}, {32, 64, 3, 0, 1, 1}, {64, 128, 3, 1, 0, 0},
        {128, 64, 1, 0, 0, 0}, {64, 128, 3, 1, 1, 0}, {128, 256, 3, 1, 0, 0},
        {256, 128, 1, 0, 0, 0}, {128, 256, 3, 0, 1, 1}, {256, 512, 3, 1, 0, 0},
        {512, 256, 1, 0, 0, 0}, {256, 512, 3, 1, 0, 0}, {512, 256, 1, 0, 0, 0},
        {256, 512, 3, 0, 1, 1}, {512, 256, 3, 1, 0, 0}, {256, 128, 1, 0, 0, 0},
        {128, 64, 3, 1, 0, 0}, {64, 32, 1, 0, 0, 0}, {32, 6, 3, 1, 0, 0}
    };

    if (gemmOK) {
        size_t off = 0;
        for (int i = 1; i <= 15; ++i) {
            int kdim = L[i].cin * L[i].ks * L[i].ks;
            int n = L[i].cout * kdim;
            prepack<<<(n + 255) / 256, 256, 0, stream>>>(
                (const float*)d_in[2 * i + 1], WHI + off, WLO + off,
                L[i].cout, kdim, kdim / 32);
            off += (size_t)n;
        }
    }

    const float* cur = x;
    int Hin = 416, Win = 416;
    size_t woff = 0;

    for (int i = 0; i < 18; ++i) {
        const auto& l = L[i];
        const int Hc = Hin + 2 * l.cpad - l.ks + 1;
        const int Wc = Win + 2 * l.cpad - l.ks + 1;
        const int Hout = l.pool ? (Hc + 2 * l.ppad - 2) / 2 + 1 : Hc;
        const int Wout = l.pool ? (Wc + 2 * l.ppad - 2) / 2 + 1 : Wc;
        float* dst = (i % 2 == 0) ? bufA : bufB;
        const float* w  = (const float*)d_in[2 * i + 1];
        const float* bb = (const float*)d_in[2 * i + 2];
        const int kdim = l.cin * l.ks * l.ks;
        const int nkb = kdim / 32;

        int nb = 16;
        if (l.pool) {
            size_t perImg = (size_t)l.cout * Hc * Wc * 4;
            while (nb && perImg * (size_t)nb > tempAvail) nb >>= 1;
        }
        const bool useG = gemmOK && i >= 1 && i <= 15 && (!l.pool || nb >= 1);

        if (useG) {
            for (int b0 = 0; b0 < B; b0 += nb) {
                const int M = nb * Hc * Wc;
                const int gx = (M + 63) / 64;
                // largest MT giving >= 512 blocks (more blocks > more density when scarce)
                int MTv = (l.cout >= 256 && (long)gx * (l.cout / 256) >= 512) ? 4
                        : (l.cout >= 128 && (long)gx * (l.cout / 128) >= 512) ? 2 : 1;
                int gy = l.cout / (MTv * 64);
                int SK = 1;
                if (!l.pool && (long)gx * gy < 512) {
                    if (nkb % 4 == 0 && (size_t)4 * l.cout * gx * 64 * 4 <= tempAvail) SK = 4;
                    else if (nkb % 2 == 0 && (size_t)2 * l.cout * gx * 64 * 4 <= tempAvail) SK = 2;
                }
                const int nkbPer = nkb / SK;
                const int Mpad = gx * 64;
                float* gout = l.pool ? (float*)TEMP
                            : (SK > 1 ? (float*)TEMP : dst);
                dim3 gr(gx, gy, SK);
#define GL(MTC, KSC, SPL)                                                      \
                conv_mfma<MTC, KSC, SPL><<<gr, 256, 0, stream>>>(              \
                    cur, WHI + woff, WLO + woff, bb, gout, l.cin, Hin, Win,    \
                    Hc, Wc, l.cout, l.cpad, b0, nb, nkb, nkbPer, Mpad)
#define G2(MTC, KSC) do { if (SK > 1) GL(MTC, KSC, true); else GL(MTC, KSC, false); } while (0)
                if (MTv == 4)      { if (l.ks == 3) G2(4, 3); else G2(4, 1); }
                else if (MTv == 2) { if (l.ks == 3) G2(2, 3); else G2(2, 1); }
                else               { if (l.ks == 3) G2(1, 3); else G2(1, 1); }
#undef G2
#undef GL
                if (SK > 1) {
                    int tot = l.cout * M;
                    sk_reduce<<<(tot + 255) / 256, 256, 0, stream>>>(
                        (const float*)TEMP, bb, dst, l.cout, Hc * Wc, M, Mpad, SK);
                }
                if (l.pool) {
                    int total = nb * l.cout * Hout * Wout;
                    maxpool_k<<<(total + 255) / 256, 256, 0, stream>>>(
                        (const float*)TEMP,
                        dst + (size_t)b0 * l.cout * Hout * Wout,
                        l.cout, Hc, Wc, Hout, Wout, l.ppad, total);
                }
            }
        } else {
            const int spatial = Hout * Wout;
#define FLAUNCH(KK, CC, PP)                                                    \
            conv_fused<KK, CC, PP><<<dim3((B * spatial + 255) / 256,           \
                                          l.cout / CC), 256, 0, stream>>>(     \
                cur, w, bb, dst, B, l.cin, Hin, Win, Hc, Wc, Hout, Wout,       \
                l.cout, l.cpad, l.ppad)
            if (l.pool)                           FLAUNCH(3, 4, true);
            else if (l.ks == 3 && l.cout == 6)    FLAUNCH(3, 6, false);
            else if (l.ks == 3)                   FLAUNCH(3, 8, false);
            else                                  FLAUNCH(1, 8, false);
#undef FLAUNCH
        }

        if (i >= 1 && i <= 15) woff += (size_t)l.cout * kdim;
        cur = dst;
        Hin = Hout;
        Win = Wout;
    }

    head_kernel<<<1, 1024, 0, stream>>>(cur, (float*)d_out, B);
}

// Round 4
// 1519.556 us; speedup vs baseline: 4.8599x; 1.0161x over previous
//
#include <hip/hip_runtime.h>
#include <math.h>

typedef short v8s __attribute__((ext_vector_type(8)));
typedef float v4f __attribute__((ext_vector_type(4)));

// ---------------- fp32 direct conv (layers 1,17,18 + fallback) --------------------
// Runtime strides allow unpadded or ring-padded in/out tensors.
template<int K, int COT, bool POOL, bool MASK, bool SWAP>
__global__ __launch_bounds__(256) void conv_fused(
    const float* __restrict__ in, const float* __restrict__ wgt,
    const float* __restrict__ bias, float* __restrict__ out,
    int B, int Cin, int Hin, int Win,
    int Hc, int Wc, int Hout, int Wout,
    int Cout, int cpad, int ppad,
    int inPS, int inRS, int inOfs, int outPS, int outRS, int outOfs)
{
    constexpr int NPY = POOL ? 2 : 1;
    constexpr int PS  = K + NPY - 1;
    const int spatial = Hout * Wout;
    const int idx = (SWAP ? blockIdx.y : blockIdx.x) * blockDim.x + threadIdx.x;
    const int cog = SWAP ? blockIdx.x : blockIdx.y;
    const int total = B * spatial;
    if (idx >= total) return;
    const int b  = idx / spatial;
    const int sp = idx - b * spatial;
    const int oy = sp / Wout;
    const int ox = sp - oy * Wout;
    const int co0 = cog * COT;

    const int cy0 = POOL ? (2 * oy - ppad) : oy;
    const int cx0 = POOL ? (2 * ox - ppad) : ox;
    const int iy0 = cy0 - cpad;
    const int ix0 = cx0 - cpad;

    bool my[PS], mx[PS];
#pragma unroll
    for (int i = 0; i < PS; i++) {
        my[i] = !MASK || ((unsigned)(iy0 + i) < (unsigned)Hin);
        mx[i] = !MASK || ((unsigned)(ix0 + i) < (unsigned)Win);
    }

    float acc[COT][NPY * NPY];
#pragma unroll
    for (int c = 0; c < COT; c++)
#pragma unroll
        for (int p = 0; p < NPY * NPY; p++) acc[c][p] = 0.f;

    const float* inB = in + inOfs + (size_t)b * Cin * inPS;
    const long wBase  = (long)co0 * Cin * K * K;

    for (int ci = 0; ci < Cin; ci++) {
        const float* ip = inB + (size_t)ci * inPS;
        float patch[PS][PS];
#pragma unroll
        for (int py = 0; py < PS; py++) {
#pragma unroll
            for (int px = 0; px < PS; px++) {
                float v = 0.f;
                if (my[py] && mx[px]) v = ip[(iy0 + py) * inRS + (ix0 + px)];
                patch[py][px] = v;
            }
        }
        const float* wp = wgt + wBase + (long)ci * K * K;
#pragma unroll
        for (int c = 0; c < COT; c++) {
#pragma unroll
            for (int kh = 0; kh < K; kh++)
#pragma unroll
            for (int kw = 0; kw < K; kw++) {
                const float wv = wp[(long)c * Cin * K * K + kh * K + kw];
#pragma unroll
                for (int dy = 0; dy < NPY; dy++)
#pragma unroll
                for (int dx = 0; dx < NPY; dx++)
                    acc[c][dy * NPY + dx] = fmaf(wv, patch[dy + kh][dx + kw],
                                                 acc[c][dy * NPY + dx]);
            }
        }
    }

#pragma unroll
    for (int c = 0; c < COT; c++) {
        float v;
        if (POOL) {
            v = -INFINITY;
#pragma unroll
            for (int dy = 0; dy < NPY; dy++)
#pragma unroll
            for (int dx = 0; dx < NPY; dx++) {
                const int cy = cy0 + dy, cx = cx0 + dx;
                if ((unsigned)cy < (unsigned)Hc && (unsigned)cx < (unsigned)Wc)
                    v = fmaxf(v, acc[c][dy * NPY + dx]);
            }
        } else {
            v = acc[c][0];
        }
        v += bias[co0 + c];
        out[outOfs + (size_t)(b * Cout + co0 + c) * outPS + oy * outRS + ox] = v;
    }
}

// ---------------- ring zero: clear the 1-wide pad ring of [planes,(H+2),(W+2)] ----
__global__ __launch_bounds__(256) void ring_zero(
    float* __restrict__ buf, int planes, int H, int W)
{
    int Wp = W + 2, Hp = H + 2;
    int ringlen = 2 * Wp + 2 * H;
    int t = blockIdx.x * 256 + threadIdx.x;
    if (t >= planes * ringlen) return;
    int p = t / ringlen, r = t - p * ringlen;
    float* pl = buf + (size_t)p * Hp * Wp;
    int idx;
    if (r < Wp) idx = r;
    else if (r < 2 * Wp) idx = (Hp - 1) * Wp + (r - Wp);
    else { int rr = r - 2 * Wp; int row = 1 + (rr >> 1); idx = row * Wp + ((rr & 1) ? (Wp - 1) : 0); }
    pl[idx] = 0.f;
}

// ---------------- weight prepack: fp32 OIHW -> MFMA A-frag tiled bf16 hi/lo --------
__device__ __forceinline__ unsigned short f2bf_rne(float x) {
    unsigned u = __float_as_uint(x);
    return (unsigned short)((u + 0x7fffu + ((u >> 16) & 1u)) >> 16);
}
__device__ __forceinline__ float bf2f(unsigned short h) {
    return __uint_as_float(((unsigned)h) << 16);
}

__global__ __launch_bounds__(256) void prepack(
    const float* __restrict__ w, unsigned short* __restrict__ hi,
    unsigned short* __restrict__ lo, int cout, int kdim, int nkb)
{
    int t = blockIdx.x * 256 + threadIdx.x;
    if (t >= cout * kdim) return;
    int co = t / kdim, k = t - co * kdim;
    int cb = co >> 4, m = co & 15, kb = k >> 5, kk = k & 31;
    int lane = ((kk >> 3) << 4) | m, j = kk & 7;
    long dst = ((long)(cb * nkb + kb) << 9) + lane * 8 + j;
    float x = w[t];
    unsigned short h = f2bf_rne(x);
    hi[dst] = h;
    lo[dst] = f2bf_rne(x - bf2f(h));
}

// ---------------- implicit-GEMM conv via MFMA, pipelined, bf16x2 3-pass ------------
// Input is ring-padded (zero ring) => NO bounds masks in the gather.
template<int MT, int KS, bool SPLIT>
__global__ __launch_bounds__(256) void conv_mfma(
    const float* __restrict__ in, const unsigned short* __restrict__ whi,
    const unsigned short* __restrict__ wlo, const float* __restrict__ bias,
    float* __restrict__ out, int Cin, int inHWp, int inWp, int Hc, int Wc,
    int Cout, int pad, int b0, int nb, int nkbTot, int nkbPer, int Mpad,
    int outHWp, int outWp)
{
    const int HW = Hc * Wc;
    const int M = nb * HW;
    const int tid = threadIdx.x;
    const int lane = tid & 63;
    const int wv = tid >> 6;
    const int spBase = blockIdx.x * 64;
    const int kb0 = SPLIT ? blockIdx.z * nkbPer : 0;
    const int kb1 = SPLIT ? kb0 + nkbPer : nkbTot;

    __shared__ unsigned short P[2][5120];   // per buf: hi rows @0, lo @2560; stride 40

    const int spoL = lane >> 2;
    int kkc[2];
    kkc[0] = (tid & 3) + 4 * wv;
    kkc[1] = kkc[0] + 16;

    const float* sptr[4];
    int soff[4];
#pragma unroll
    for (int j = 0; j < 4; ++j) {
        int sp = spBase + spoL + 16 * j;
        int q = sp < M ? sp : M - 1;
        int b = q / HW; int r = q - b * HW;
        int soy = r / Wc, sox = r - soy * Wc;
        soff[j] = (soy + 1) * inWp + (sox + 1);
        sptr[j] = in + (size_t)(b0 + b) * Cin * inHWp;
    }

    int ci[2], r9[2], koff[2];
#pragma unroll
    for (int m = 0; m < 2; ++m) {
        int k = kb0 * 32 + kkc[m];
        if (KS == 3) {
            ci[m] = k / 9; r9[m] = k - 9 * ci[m];
            int d3 = (r9[m] >= 3) + (r9[m] >= 6);
            koff[m] = ci[m] * inHWp + (d3 - pad) * inWp + (r9[m] - 3 * d3 - pad);
        } else { ci[m] = k; koff[m] = k * inHWp; }
    }

    float rv[8];
#define STAGE()                                                                \
    {                                                                          \
        _Pragma("unroll")                                                      \
        for (int m = 0; m < 2; ++m)                                            \
        _Pragma("unroll")                                                      \
        for (int j = 0; j < 4; ++j)                                            \
            rv[m * 4 + j] = sptr[j][koff[m] + soff[j]];                        \
    }
#define ADVANCE()                                                              \
    {                                                                          \
        _Pragma("unroll")                                                      \
        for (int m = 0; m < 2; ++m) {                                          \
            if (KS == 3) {                                                     \
                r9[m] += 5; int c = r9[m] >= 9; r9[m] -= c ? 9 : 0;            \
                ci[m] += 3 + c;                                                \
                int d3 = (r9[m] >= 3) + (r9[m] >= 6);                          \
                koff[m] = ci[m] * inHWp + (d3 - pad) * inWp                    \
                        + (r9[m] - 3 * d3 - pad);                              \
            } else { koff[m] += 32 * inHWp; }                                  \
        }                                                                      \
    }

    STAGE();

    const int g0 = blockIdx.y * (MT * 4) + wv * MT;
    const unsigned short* whp[MT];
    const unsigned short* wlp[MT];
#pragma unroll
    for (int mt = 0; mt < MT; ++mt) {
        size_t base = (((size_t)(g0 + mt) * nkbTot + kb0) << 9) + lane * 8;
        whp[mt] = whi + base; wlp[mt] = wlo + base;
    }

    v4f acc[MT][4];
    {
        v4f z = {0.f, 0.f, 0.f, 0.f};
#pragma unroll
        for (int mt = 0; mt < MT; ++mt)
#pragma unroll
            for (int nt = 0; nt < 4; ++nt) acc[mt][nt] = z;
    }

    for (int kb = kb0; kb < kb1; ++kb) {
        unsigned short* Ph = P[kb & 1];
#pragma unroll
        for (int m = 0; m < 2; ++m)
#pragma unroll
        for (int j = 0; j < 4; ++j) {
            float v = rv[m * 4 + j];
            unsigned vb = __float_as_uint(v);
            float res = v - __uint_as_float(vb & 0xffff0000u);
            int a = (spoL + 16 * j) * 40 + kkc[m];
            Ph[a] = (unsigned short)(vb >> 16);
            Ph[2560 + a] = (unsigned short)(__float_as_uint(res) >> 16);
        }
        __syncthreads();

        v8s wh[MT], wl[MT];
#pragma unroll
        for (int mt = 0; mt < MT; ++mt) {
            wh[mt] = *(const v8s*)whp[mt];
            wl[mt] = *(const v8s*)wlp[mt];
            whp[mt] += 512; wlp[mt] += 512;
        }

        if (kb + 1 < kb1) { ADVANCE(); STAGE(); }   // overlaps MFMA below

#pragma unroll
        for (int nt = 0; nt < 4; ++nt) {
            int ro = (nt * 16 + (lane & 15)) * 40 + (lane >> 4) * 8;
            v8s ph = *(const v8s*)(Ph + ro);
            v8s pl = *(const v8s*)(Ph + 2560 + ro);
#pragma unroll
            for (int mt = 0; mt < MT; ++mt) {
                acc[mt][nt] = __builtin_amdgcn_mfma_f32_16x16x32_bf16(wh[mt], ph, acc[mt][nt], 0, 0, 0);
                acc[mt][nt] = __builtin_amdgcn_mfma_f32_16x16x32_bf16(wh[mt], pl, acc[mt][nt], 0, 0, 0);
                acc[mt][nt] = __builtin_amdgcn_mfma_f32_16x16x32_bf16(wl[mt], ph, acc[mt][nt], 0, 0, 0);
            }
        }
    }
#undef STAGE
#undef ADVANCE

    const int qrow = (lane >> 4) * 4;
    if (SPLIT) {
        float* pz = out + (size_t)blockIdx.z * Cout * Mpad;
#pragma unroll
        for (int mt = 0; mt < MT; ++mt) {
            int co = (g0 + mt) * 16 + qrow;
#pragma unroll
            for (int nt = 0; nt < 4; ++nt) {
                int sp = spBase + nt * 16 + (lane & 15);
                if (sp < M) {
#pragma unroll
                    for (int r = 0; r < 4; ++r)
                        pz[(size_t)(co + r) * Mpad + sp] = acc[mt][nt][r];
                }
            }
        }
    } else {
#pragma unroll
        for (int mt = 0; mt < MT; ++mt) {
            int co = (g0 + mt) * 16 + qrow;
            float bsv[4];
#pragma unroll
            for (int r = 0; r < 4; ++r) bsv[r] = bias[co + r];
#pragma unroll
            for (int nt = 0; nt < 4; ++nt) {
                int sp = spBase + nt * 16 + (lane & 15);
                if (sp < M) {
                    int b = sp / HW, rsp = sp - b * HW;
                    int y = rsp / Wc, xx = rsp - y * Wc;
                    float* op = out + (size_t)(b * Cout + co) * outHWp
                              + (size_t)(y + 1) * outWp + (xx + 1);
#pragma unroll
                    for (int r = 0; r < 4; ++r)
                        op[(size_t)r * outHWp] = acc[mt][nt][r] + bsv[r];
                }
            }
        }
    }
}

// ---------------- split-K reduce (adds bias, writes padded) ------------------------
__global__ __launch_bounds__(256) void sk_reduce(
    const float* __restrict__ part, const float* __restrict__ bias,
    float* __restrict__ out, int Cout, int HW, int Wc, int M, int Mpad, int SK,
    int outHWp, int outWp)
{
    int t = blockIdx.x * 256 + threadIdx.x;
    if (t >= Cout * M) return;
    int co = t / M, m = t - co * M;
    float s = bias[co];
    for (int k = 0; k < SK; ++k)
        s += part[((size_t)k * Cout + co) * Mpad + m];
    int b = m / HW, rsp = m - b * HW;
    int y = rsp / Wc, xx = rsp - y * Wc;
    out[(size_t)(b * Cout + co) * outHWp + (size_t)(y + 1) * outWp + (xx + 1)] = s;
}

// ---------------- 2x2/2 maxpool (torch floor mode, -inf pad), padded in/out --------
__global__ __launch_bounds__(256) void maxpool_k(
    const float* __restrict__ in, float* __restrict__ out,
    int Hc, int Wc, int Hp, int Wp, int p, int total,
    int inHWp, int inWp, int outHWp, int outWp)
{
    int t = blockIdx.x * 256 + threadIdx.x;
    if (t >= total) return;
    int wp2 = Hp * Wp;
    int bc = t / wp2; int r = t - bc * wp2;
    int y = r / Wp, xx = r - y * Wp;
    int y0 = 2 * y - p, x0 = 2 * xx - p;
    const float* ip = in + (size_t)bc * inHWp;
    float v = -INFINITY;
#pragma unroll
    for (int dy = 0; dy < 2; ++dy)
#pragma unroll
    for (int dx = 0; dx < 2; ++dx) {
        int yy = y0 + dy, xc = x0 + dx;
        if ((unsigned)yy < (unsigned)Hc && (unsigned)xc < (unsigned)Wc)
            v = fmaxf(v, ip[(yy + 1) * inWp + (xc + 1)]);
    }
    out[(size_t)bc * outHWp + (size_t)(y + 1) * outWp + (xx + 1)] = v;
}

// ---------------- head (reads unpadded final feat) ---------------------------------
__global__ __launch_bounds__(1024) void head_kernel(
    const float* __restrict__ x, float* __restrict__ out, int B)
{
    const int W = 13, H = 13;
    const float gx = 0.567f, gy = 0.469f, gw = 0.206f, gh = 0.53f;
    const int tid = threadIdx.x;
    const int total = B * W * H;
    float lsum = 0.f;
    for (int i = tid; i < total; i += blockDim.x) {
        const int b = i / (W * H);
        const int r = i - b * W * H;
        const int j = r / H;
        const int k = r - j * H;
        float v[6];
#pragma unroll
        for (int c = 0; c < 6; c++) {
            v[c] = x[((b * 6 + c) * H + k) * W + j];
            out[((b * W + j) * H + k) * 6 + c] = v[c];
        }
        const float px = (j + v[2]) / (float)W;
        const float py = (k + v[3]) / (float)H;
        const float pw = expf(v[4]) / (float)W;
        const float ph = expf(v[5]) / (float)H;
        float iw = fminf(px + pw * 0.5f, gx + gw * 0.5f)
                 - fmaxf(px - pw * 0.5f, gx - gw * 0.5f);
        iw = fmaxf(iw, 0.f);
        float ih = fminf(py + ph * 0.5f, gy + gh * 0.5f)
                 - fmaxf(py - ph * 0.5f, gy - gh * 0.5f);
        ih = fmaxf(ih, 0.f);
        const float inter = iw * ih;
        const float iou = inter / (pw * ph + gw * gh - inter);
        const float tx = gx * W - (float)j;
        const float ty = gy * H - (float)k;
        const float tw = logf(gw * W);
        const float th = logf(gh * H);
        const float l1 = fabsf(tx - v[2]) + fabsf(ty - v[3])
                       + fabsf(tw - v[4]) + fabsf(th - v[5]);
        if (iou > 0.5f) lsum += l1;
    }
    __shared__ float red[1024];
    red[tid] = lsum;
    __syncthreads();
    for (int s = blockDim.x / 2; s > 0; s >>= 1) {
        if (tid < s) red[tid] += red[tid + s];
        __syncthreads();
    }
    if (tid == 0) out[total * 6] = red[0];
}

// ---------------- host ------------------------------------------------------------
extern "C" void kernel_launch(void* const* d_in, const int* in_sizes, int n_in,
                              void* d_out, int out_size, void* d_ws, size_t ws_size,
                              hipStream_t stream)
{
    (void)in_sizes; (void)n_in; (void)out_size;
    const float* x = (const float*)d_in[0];
    const int B = 16;
    const size_t MB = 1024 * 1024;
    char* ws = (char*)d_ws;
    float* bufA = (float*)ws;                                  // <= 93 MB (padded)
    float* bufB = (float*)(ws + 93 * MB);                      // <= 48 MB (padded)
    unsigned short* WHI = (unsigned short*)(ws + 141 * MB);    // <= 12 MB
    unsigned short* WLO = (unsigned short*)(ws + 153 * MB);    // <= 12 MB
    char* TEMP = ws + 165 * MB;
    const bool gemmOK = ws_size >= 166 * MB;
    const size_t tempAvail = ws_size > 165 * MB ? ws_size - 165 * MB : 0;

    static const struct { int cin, cout, ks, cpad, pool, ppad; } L[18] = {
        {3,  32, 3, 0, 1, 1}, {32, 64, 3, 0, 1, 1}, {64, 128, 3, 1, 0, 0},
        {128, 64, 1, 0, 0, 0}, {64, 128, 3, 1, 1, 0}, {128, 256, 3, 1, 0, 0},
        {256, 128, 1, 0, 0, 0}, {128, 256, 3, 0, 1, 1}, {256, 512, 3, 1, 0, 0},
        {512, 256, 1, 0, 0, 0}, {256, 512, 3, 1, 0, 0}, {512, 256, 1, 0, 0, 0},
        {256, 512, 3, 0, 1, 1}, {512, 256, 3, 1, 0, 0}, {256, 128, 1, 0, 0, 0},
        {128, 64, 3, 1, 0, 0}, {64, 32, 1, 0, 0, 0}, {32, 6, 3, 1, 0, 0}
    };
    // producer layers whose output ring must be zero (consumer conv has pad=1)
    static const bool RING[18] = {0,1,0,1,1,0,0,1,0,1,0,0,1,0,1,0,1,0};

    if (gemmOK) {
        size_t off = 0;
        for (int i = 1; i <= 15; ++i) {
            int kdim = L[i].cin * L[i].ks * L[i].ks;
            int n = L[i].cout * kdim;
            prepack<<<(n + 255) / 256, 256, 0, stream>>>(
                (const float*)d_in[2 * i + 1], WHI + off, WLO + off,
                L[i].cout, kdim, kdim / 32);
            off += (size_t)n;
        }
    }

    const float* cur = x;
    int Hin = 416, Win = 416;
    size_t woff = 0;

    for (int i = 0; i < 18; ++i) {
        const auto& l = L[i];
        const int Hc = Hin + 2 * l.cpad - l.ks + 1;
        const int Wc = Win + 2 * l.cpad - l.ks + 1;
        const int Hout = l.pool ? (Hc + 2 * l.ppad - 2) / 2 + 1 : Hc;
        const int Wout = l.pool ? (Wc + 2 * l.ppad - 2) / 2 + 1 : Wc;
        float* dst = (i % 2 == 0) ? bufA : bufB;
        const float* w  = (const float*)d_in[2 * i + 1];
        const float* bb = (const float*)d_in[2 * i + 2];
        const int kdim = l.cin * l.ks * l.ks;
        const int nkb = kdim / 32;

        // input strides (x itself is unpadded; intermediates are ring-padded)
        const int inRS  = (i == 0) ? Win : (Win + 2);
        const int inPS  = (i == 0) ? Hin * Win : (Hin + 2) * (Win + 2);
        const int inOfs = (i == 0) ? 0 : (inRS + 1);
        // output strides (final layer unpadded)
        const bool outPad = (i != 17);
        const int outRS  = outPad ? (Wout + 2) : Wout;
        const int outPS  = outPad ? (Hout + 2) * (Wout + 2) : Hout * Wout;
        const int outOfs = outPad ? (outRS + 1) : 0;
        // pre-pool conv temp strides (padded)
        const int tRS = Wc + 2, tPS = (Hc + 2) * (Wc + 2);

        if (RING[i]) {
            int planes = B * l.cout;
            int ringlen = 2 * (Wout + 2) + 2 * Hout;
            ring_zero<<<(planes * ringlen + 255) / 256, 256, 0, stream>>>(
                dst, planes, Hout, Wout);
        }

        int nb = 16;
        if (l.pool) {
            size_t perImg = (size_t)l.cout * tPS * 4;
            while (nb && perImg * (size_t)nb > tempAvail) nb >>= 1;
        }
        const bool useG = gemmOK && i >= 1 && i <= 15 && (!l.pool || nb >= 1);

        if (useG) {
            for (int b0 = 0; b0 < B; b0 += nb) {
                const int M = nb * Hc * Wc;
                const int gx = (M + 63) / 64;
                int MTv = (l.cout >= 256 && (long)gx * (l.cout / 256) >= 512) ? 4
                        : (l.cout >= 128 && (long)gx * (l.cout / 128) >= 512) ? 2 : 1;
                int gy = l.cout / (MTv * 64);
                int SK = 1;
                if (!l.pool && (long)gx * gy < 512) {
                    if (nkb % 4 == 0 && (size_t)4 * l.cout * gx * 64 * 4 <= tempAvail) SK = 4;
                    else if (nkb % 2 == 0 && (size_t)2 * l.cout * gx * 64 * 4 <= tempAvail) SK = 2;
                }
                const int nkbPer = nkb / SK;
                const int Mpad = gx * 64;
                float* gout = l.pool ? (float*)TEMP : (SK > 1 ? (float*)TEMP : dst);
                const int gHWp = l.pool ? tPS : (SK > 1 ? 0 : outPS);
                const int gWp  = l.pool ? tRS : (SK > 1 ? 0 : outRS);
                dim3 gr(gx, gy, SK);
#define GL(MTC, KSC, SPL)                                                      \
                conv_mfma<MTC, KSC, SPL><<<gr, 256, 0, stream>>>(              \
                    cur, WHI + woff, WLO + woff, bb, gout, l.cin, inPS, inRS,  \
                    Hc, Wc, l.cout, l.cpad, b0, nb, nkb, nkbPer, Mpad,         \
                    gHWp, gWp)
#define G2(MTC, KSC) do { if (SK > 1) GL(MTC, KSC, true); else GL(MTC, KSC, false); } while (0)
                if (MTv == 4)      { if (l.ks == 3) G2(4, 3); else G2(4, 1); }
                else if (MTv == 2) { if (l.ks == 3) G2(2, 3); else G2(2, 1); }
                else               { if (l.ks == 3) G2(1, 3); else G2(1, 1); }
#undef G2
#undef GL
                if (SK > 1) {
                    int tot = l.cout * M;
                    sk_reduce<<<(tot + 255) / 256, 256, 0, stream>>>(
                        (const float*)TEMP, bb, dst, l.cout, Hc * Wc, Wc, M,
                        Mpad, SK, outPS, outRS);
                }
                if (l.pool) {
                    int total = nb * l.cout * Hout * Wout;
                    maxpool_k<<<(total + 255) / 256, 256, 0, stream>>>(
                        (const float*)TEMP,
                        dst + (size_t)b0 * l.cout * outPS,
                        Hc, Wc, Hout, Wout, l.ppad, total, tPS, tRS, outPS, outRS);
                }
            }
        } else {
            const int spatial = Hout * Wout;
#define FL(KK, CC, PP, MM, SW)                                                 \
            conv_fused<KK, CC, PP, MM, SW><<<                                  \
                SW ? dim3(l.cout / CC, (B * spatial + 255) / 256)              \
                   : dim3((B * spatial + 255) / 256, l.cout / CC),             \
                256, 0, stream>>>(                                             \
                cur, w, bb, dst, B, l.cin, Hin, Win, Hc, Wc, Hout, Wout,       \
                l.cout, l.cpad, l.ppad, inPS, inRS, inOfs, outPS, outRS, outOfs)
            if (i == 0)                           FL(3, 8, true, true, true);
            else if (i == 16)                     FL(1, 8, false, false, false);
            else if (i == 17)                     FL(3, 6, false, false, false);
            else if (l.pool)                      FL(3, 4, true, true, false);
            else if (l.ks == 3)                   FL(3, 8, false, true, false);
            else                                  FL(1, 8, false, true, false);
#undef FL
        }

        if (i >= 1 && i <= 15) woff += (size_t)l.cout * kdim;
        cur = dst;
        Hin = Hout;
        Win = Wout;
    }

    head_kernel<<<1, 1024, 0, stream>>>(cur, (float*)d_out, B);
}